// Round 1
// baseline (2643.726 us; speedup 1.0000x reference)
//
#include <hip/hip_runtime.h>
#include <math.h>

// Problem constants (from reference)
constexpr int D_   = 512;   // d_model
constexpr int H_   = 128;   // extractor hidden
constexpr int P_   = 10;    // n_programs
constexpr int MAXO = 4;
constexpr int TB_  = 64;    // token tile
constexpr int KC_  = 32;    // K chunk

__device__ __forceinline__ float gelu_exact(float x) {
    return 0.5f * x * (1.0f + erff(x * 0.70710678118654752f));
}

// hours, minutes, days  <- total minutes (match reference op order exactly,
// using true IEEE division so floor() bins identically to numpy)
__device__ __forceinline__ void time_decomp(float t, float& hr, float& mi, float& dy) {
    float days = floorf(t / 1440.0f);
    float rem  = t - days * 1440.0f;
    float hours = floorf(rem / 60.0f);
    float minutes = rem - hours * 60.0f;
    hr = hours; mi = minutes; dy = days;
}

__global__ __launch_bounds__(256) void extractor_kernel(
    const float* __restrict__ hidden,   // [B, D]
    const int*   __restrict__ pids,     // [B]
    const float* __restrict__ W1,       // [P, D, H]
    const float* __restrict__ b1,       // [P, H]
    const float* __restrict__ W2,       // [P, H, MAXO]
    const float* __restrict__ b2,       // [P, MAXO]
    float* __restrict__ out_results,    // [B, 3]
    float* __restrict__ out_ops,        // [P, B, MAXO]
    int B)
{
    __shared__ float As[KC_][TB_];      // [k][m] transposed hidden tile
    __shared__ float Bs[KC_][H_];       // [k][n] W1 tile
    __shared__ float W2s[MAXO * H_];    // transposed: [o][h]

    const int p   = blockIdx.y;
    const int b0  = blockIdx.x * TB_;
    const int tid = threadIdx.x;
    const int c   = tid & 15;   // column group: n = c*8 .. c*8+7
    const int r   = tid >> 4;   // row group:    m = r*4 .. r*4+3

    const float* W1p = W1 + (size_t)p * D_ * H_;

    // stage W2 (transposed) once; first chunk's __syncthreads covers it
    if (tid < H_) {
        float4 w = reinterpret_cast<const float4*>(W2 + (size_t)p * H_ * MAXO)[tid];
        W2s[0 * H_ + tid] = w.x;
        W2s[1 * H_ + tid] = w.y;
        W2s[2 * H_ + tid] = w.z;
        W2s[3 * H_ + tid] = w.w;
    }

    float acc[4][8];
#pragma unroll
    for (int i = 0; i < 4; ++i)
#pragma unroll
        for (int j = 0; j < 8; ++j) acc[i][j] = 0.0f;

    for (int k0 = 0; k0 < D_; k0 += KC_) {
        __syncthreads();   // protect LDS from previous chunk's readers
        // stage A: 64 rows x 32 k, stored transposed [k][m]
#pragma unroll
        for (int it = 0; it < 2; ++it) {
            int i  = tid + it * 256;      // float4 index 0..511
            int m  = i >> 3;              // 8 float4 per row
            int kk = (i & 7) * 4;
            float4 v = *reinterpret_cast<const float4*>(
                hidden + (size_t)(b0 + m) * D_ + k0 + kk);
            As[kk + 0][m] = v.x;
            As[kk + 1][m] = v.y;
            As[kk + 2][m] = v.z;
            As[kk + 3][m] = v.w;
        }
        // stage B: 32 k x 128 n
#pragma unroll
        for (int it = 0; it < 4; ++it) {
            int i  = tid + it * 256;      // float4 index 0..1023
            int kk = i >> 5;              // 32 float4 per row
            int n4 = (i & 31) * 4;
            *reinterpret_cast<float4*>(&Bs[kk][n4]) =
                *reinterpret_cast<const float4*>(W1p + (size_t)(k0 + kk) * H_ + n4);
        }
        __syncthreads();
#pragma unroll
        for (int k = 0; k < KC_; ++k) {
            float a[4], bv[8];
            *reinterpret_cast<float4*>(&a[0])  = *reinterpret_cast<const float4*>(&As[k][r * 4]);
            *reinterpret_cast<float4*>(&bv[0]) = *reinterpret_cast<const float4*>(&Bs[k][c * 8]);
            *reinterpret_cast<float4*>(&bv[4]) = *reinterpret_cast<const float4*>(&Bs[k][c * 8 + 4]);
#pragma unroll
            for (int i = 0; i < 4; ++i)
#pragma unroll
                for (int j = 0; j < 8; ++j)
                    acc[i][j] = fmaf(a[i], bv[j], acc[i][j]);
        }
    }

    // ---- epilogue: bias + exact gelu + GEMM2 partials over this thread's 8 h ----
    const float* b1p = b1 + p * H_;
    float po[4][4];
#pragma unroll
    for (int i = 0; i < 4; ++i)
#pragma unroll
        for (int o = 0; o < 4; ++o) po[i][o] = 0.0f;

#pragma unroll
    for (int j = 0; j < 8; ++j) {
        int h = c * 8 + j;
        float bb = b1p[h];
#pragma unroll
        for (int i = 0; i < 4; ++i) {
            float g = gelu_exact(acc[i][j] + bb);
#pragma unroll
            for (int o = 0; o < 4; ++o)
                po[i][o] = fmaf(g, W2s[o * H_ + h], po[i][o]);
        }
    }

    // butterfly reduce across the 16 c-lanes (same r group)
#pragma unroll
    for (int off = 1; off < 16; off <<= 1) {
#pragma unroll
        for (int i = 0; i < 4; ++i)
#pragma unroll
            for (int o = 0; o < 4; ++o)
                po[i][o] += __shfl_xor(po[i][o], off, 64);
    }

    const float bb2_0 = b2[p * 4 + 0];
    const float bb2_1 = b2[p * 4 + 1];
    const float bb2_2 = b2[p * 4 + 2];
    const float bb2_3 = b2[p * 4 + 3];

    if (c < 4) {
#pragma unroll
        for (int i = 0; i < 4; ++i) {
            if (c == i) {
                int b = b0 + r * 4 + i;
                float o0 = po[i][0] + bb2_0;
                float o1 = po[i][1] + bb2_1;
                float o2 = po[i][2] + bb2_2;
                float o3 = po[i][3] + bb2_3;
                float4 ov = make_float4(o0, o1, o2, o3);
                *reinterpret_cast<float4*>(out_ops + ((size_t)p * B + b) * MAXO) = ov;

                int pid = pids[b];
                if (pid == p) {
                    float a0 = rintf(o0), a1 = rintf(o1), a2 = rintf(o2), a3 = rintf(o3);
                    float r0 = 0.0f, r1 = 0.0f, r2 = 0.0f;
                    switch (p) {
                        case 0: r0 = a0 + a1; break;                       // IntAdd
                        case 1: r0 = a0 - a1; break;                       // IntSub
                        case 2: r0 = a0 * a1; break;                       // IntMul
                        case 3: {                                          // Mod (floor-mod)
                            float bs = (a1 == 0.0f) ? 1.0f : a1;
                            float m = fmodf(a0, bs);
                            if (m != 0.0f && ((m < 0.0f) != (bs < 0.0f))) m += bs;
                            r0 = m;
                        } break;
                        case 4: {                                          // FloorDiv
                            float bs = (a1 == 0.0f) ? 1.0f : a1;
                            r0 = floorf(a0 / bs);
                        } break;
                        case 5: {                                          // TimeAdd
                            float t = a0 * 60.0f + a1 + a2 * 60.0f + a3;
                            time_decomp(t, r0, r1, r2);
                        } break;
                        case 6: {                                          // TimeSub
                            float t = a0 * 60.0f + a1 - (a2 * 60.0f + a3);
                            time_decomp(t, r0, r1, r2);
                        } break;
                        case 7: {                                          // DurationBetween
                            float t = fabsf(a0 * 60.0f + a1 - (a2 * 60.0f + a3));
                            time_decomp(t, r0, r1, r2);
                        } break;
                        case 8: r0 = (a0 > a1) ? 1.0f : 0.0f; break;       // Greater
                        case 9: r0 = (a0 == a1) ? 1.0f : 0.0f; break;      // Equal
                    }
                    size_t ob = (size_t)b * 3;
                    out_results[ob + 0] = r0;
                    out_results[ob + 1] = r1;
                    out_results[ob + 2] = r2;
                }
            }
        }
    }
}

// One wave per token; Wr staged in LDS with row stride 12 (16B-aligned, good banks)
__global__ __launch_bounds__(256) void router_kernel(
    const float* __restrict__ hidden,   // [B, D]
    const float* __restrict__ Wr,       // [D, P]
    const float* __restrict__ br,       // [P]
    const int*   __restrict__ pids,     // [B]
    float* __restrict__ out_router,     // [B, P]
    float* __restrict__ out_pids,       // [B] as float
    int B)
{
    __shared__ float Wrs[D_ * 12];
    const int tid = threadIdx.x;
    for (int i = tid; i < D_ * P_; i += 256) {
        int k = i / P_;
        int q = i - k * P_;
        Wrs[k * 12 + q] = Wr[i];
    }
    __syncthreads();

    const int lane = tid & 63;
    const int wv   = tid >> 6;
    const int b    = blockIdx.x * 4 + wv;
    const float* hrow = hidden + (size_t)b * D_;

    float acc[P_];
#pragma unroll
    for (int q = 0; q < P_; ++q) acc[q] = 0.0f;

#pragma unroll
    for (int j = 0; j < 8; ++j) {
        int k = j * 64 + lane;
        float hv = hrow[k];
        float wv12[12];
        *reinterpret_cast<float4*>(&wv12[0]) = *reinterpret_cast<const float4*>(&Wrs[k * 12 + 0]);
        *reinterpret_cast<float4*>(&wv12[4]) = *reinterpret_cast<const float4*>(&Wrs[k * 12 + 4]);
        *reinterpret_cast<float2*>(&wv12[8]) = *reinterpret_cast<const float2*>(&Wrs[k * 12 + 8]);
#pragma unroll
        for (int q = 0; q < P_; ++q) acc[q] = fmaf(hv, wv12[q], acc[q]);
    }

#pragma unroll
    for (int off = 1; off < 64; off <<= 1) {
#pragma unroll
        for (int q = 0; q < P_; ++q)
            acc[q] += __shfl_xor(acc[q], off, 64);
    }

    if (lane == 0) {
        float* o = out_router + (size_t)b * P_;
#pragma unroll
        for (int q = 0; q < P_; ++q) o[q] = acc[q] + br[q];
        out_pids[b] = (float)pids[b];
    }
}

extern "C" void kernel_launch(void* const* d_in, const int* in_sizes, int n_in,
                              void* d_out, int out_size, void* d_ws, size_t ws_size,
                              hipStream_t stream) {
    const float* hidden = (const float*)d_in[0];
    const int*   pids   = (const int*)  d_in[1];
    const float* Wr     = (const float*)d_in[2];
    const float* br     = (const float*)d_in[3];
    const float* W1     = (const float*)d_in[4];
    const float* b1     = (const float*)d_in[5];
    const float* W2     = (const float*)d_in[6];
    const float* b2     = (const float*)d_in[7];

    const int B = in_sizes[1];   // program_ids has B elements

    float* out         = (float*)d_out;
    float* out_results = out;                                   // [B,3]
    float* out_router  = out + (size_t)B * 3;                   // [B,10]
    float* out_ops     = out + (size_t)B * 13;                  // [P,B,4]
    float* out_pids    = out + (size_t)B * 13 + (size_t)P_ * B * MAXO; // [B]

    dim3 gridE(B / TB_, P_);
    extractor_kernel<<<gridE, 256, 0, stream>>>(hidden, pids, W1, b1, W2, b2,
                                                out_results, out_ops, B);
    router_kernel<<<B / 4, 256, 0, stream>>>(hidden, Wr, br, pids,
                                             out_router, out_pids, B);
}

// Round 2
// 913.737 us; speedup vs baseline: 2.8933x; 2.8933x over previous
//
#include <hip/hip_runtime.h>
#include <math.h>

constexpr int D_   = 512;   // d_model
constexpr int H_   = 128;   // extractor hidden
constexpr int P_   = 10;    // n_programs
constexpr int MAXO = 4;
constexpr int BM   = 128;   // token tile
constexpr int BK   = 32;    // K chunk (= one MFMA K step)

typedef _Float16 f16;
typedef f16 f16x4 __attribute__((ext_vector_type(4)));
typedef f16 f16x8 __attribute__((ext_vector_type(8)));
typedef float f32x4 __attribute__((ext_vector_type(4)));

__device__ __forceinline__ float gelu_exact(float x) {
    return 0.5f * x * (1.0f + erff(x * 0.70710678118654752f));
}

__device__ __forceinline__ void time_decomp(float t, float& hr, float& mi, float& dy) {
    float days = floorf(t / 1440.0f);
    float rem  = t - days * 1440.0f;
    float hours = floorf(rem / 60.0f);
    float minutes = rem - hours * 60.0f;
    hr = hours; mi = minutes; dy = days;
}

__device__ __forceinline__ void g2l16(const f16* g, f16* l) {
    __builtin_amdgcn_global_load_lds(
        (const __attribute__((address_space(1))) void*)g,
        (__attribute__((address_space(3))) void*)l, 16, 0, 0);
}

// W1 [P][D][H] f32  ->  W1T_hi / W1T_lo  [P][H][D] f16 (transposed + split)
__global__ __launch_bounds__(256) void cvt_w1_kernel(
    const float* __restrict__ W1, f16* __restrict__ hi, f16* __restrict__ lo)
{
    int i = blockIdx.x * 256 + threadIdx.x;      // < P_*D_*H_
    float x = W1[i];
    f16 h = (f16)x;
    f16 L = (f16)(x - (float)h);
    int dh = i % (D_ * H_);
    int p  = i / (D_ * H_);
    int d  = dh / H_;
    int hh = dh % H_;
    size_t o = ((size_t)(p * H_ + hh)) * D_ + d;
    hi[o] = h; lo[o] = L;
}

__global__ __launch_bounds__(256) void extractor_kernel(
    const float* __restrict__ hidden,   // [B, D] f32
    const int*   __restrict__ pids,     // [B]
    const f16*   __restrict__ W1Thi,    // [P][H][D]
    const f16*   __restrict__ W1Tlo,    // [P][H][D]
    const float* __restrict__ b1,       // [P, H]
    const float* __restrict__ W2,       // [P, H, MAXO]
    const float* __restrict__ b2,       // [P, MAXO]
    float* __restrict__ out_results,    // [B, 3]
    float* __restrict__ out_ops,        // [P, B, MAXO]
    int B)
{
    __shared__ f16 Ahi[BM * BK], Alo[BM * BK];   // [m][k] row-major
    __shared__ f16 Bhi[H_ * BK], Blo[H_ * BK];   // [h][k] row-major (W1^T chunk)
    __shared__ float W2s[H_ * 4];                // [h][o]
    __shared__ float red[2][BM][4];              // per-wn GEMM2 partials

    const int bid  = blockIdx.x;
    const int p    = bid % P_;           // program varies fastest -> hidden tile L3 reuse
    const int b0   = (bid / P_) * BM;
    const int tid  = threadIdx.x;
    const int l    = tid & 63;
    const int w    = tid >> 6;
    const int wm   = w >> 1, wn = w & 1; // wave tile: 64 tokens x 64 h
    const int l15  = l & 15, l4 = l >> 4;

    if (tid < H_) {
        ((f32x4*)W2s)[tid] = ((const f32x4*)(W2 + (size_t)p * H_ * 4))[tid];
    }

    f32x4 acc[4][4];
#pragma unroll
    for (int mi = 0; mi < 4; ++mi)
#pragma unroll
        for (int ni = 0; ni < 4; ++ni) acc[mi][ni] = (f32x4){0.f, 0.f, 0.f, 0.f};

    const f16* Bhig = W1Thi + (size_t)p * H_ * D_;
    const f16* Blog = W1Tlo + (size_t)p * H_ * D_;

    for (int kc = 0; kc < D_ / BK; ++kc) {
        __syncthreads();   // previous chunk's readers done (also covers W2s staging)

        // ---- stage B chunk [128 h][32 k] hi/lo via async global->LDS (16B/lane) ----
#pragma unroll
        for (int t = 0; t < 2; ++t) {
            int h0 = w * 32 + t * 16;                       // wave-uniform
            size_t ge = (size_t)(h0 + (l >> 2)) * D_ + kc * BK + (l & 3) * 8;
            g2l16(Bhig + ge, &Bhi[h0 * BK]);
            g2l16(Blog + ge, &Blo[h0 * BK]);
        }

        // ---- stage A chunk [128 m][32 k]: load f32, split to f16 hi/lo ----
#pragma unroll
        for (int it = 0; it < 4; ++it) {
            int i  = tid + it * 256;        // float4 id, 1024 total
            int m  = i >> 3;
            int k4 = (i & 7) * 4;
            f32x4 v = *(const f32x4*)(hidden + (size_t)(b0 + m) * D_ + kc * BK + k4);
            f16x4 vh, vl;
#pragma unroll
            for (int j = 0; j < 4; ++j) {
                f16 hj = (f16)v[j];
                vh[j] = hj;
                vl[j] = (f16)(v[j] - (float)hj);
            }
            *(f16x4*)&Ahi[m * BK + k4] = vh;
            *(f16x4*)&Alo[m * BK + k4] = vl;
        }
        __syncthreads();   // drains vmcnt (global_load_lds) + lgkm (ds_write)

        // ---- MFMA: 16 frag-tiles x 3 split-terms ----
        f16x8 bh[4], bl[4];
#pragma unroll
        for (int ni = 0; ni < 4; ++ni) {
            int hrow = wn * 64 + ni * 16 + l15;
            bh[ni] = *(const f16x8*)&Bhi[hrow * BK + l4 * 8];
            bl[ni] = *(const f16x8*)&Blo[hrow * BK + l4 * 8];
        }
#pragma unroll
        for (int mi = 0; mi < 4; ++mi) {
            int mrow = wm * 64 + mi * 16 + l15;
            f16x8 a_h = *(const f16x8*)&Ahi[mrow * BK + l4 * 8];
            f16x8 a_l = *(const f16x8*)&Alo[mrow * BK + l4 * 8];
#pragma unroll
            for (int ni = 0; ni < 4; ++ni) {
                acc[mi][ni] = __builtin_amdgcn_mfma_f32_16x16x32_f16(a_l, bh[ni], acc[mi][ni], 0, 0, 0);
                acc[mi][ni] = __builtin_amdgcn_mfma_f32_16x16x32_f16(a_h, bl[ni], acc[mi][ni], 0, 0, 0);
                acc[mi][ni] = __builtin_amdgcn_mfma_f32_16x16x32_f16(a_h, bh[ni], acc[mi][ni], 0, 0, 0);
            }
        }
    }

    // ---- epilogue: bias + gelu + GEMM2 (H->4) ----
    float b1v[4];
#pragma unroll
    for (int ni = 0; ni < 4; ++ni)
        b1v[ni] = b1[p * H_ + wn * 64 + ni * 16 + l15];

#pragma unroll
    for (int mi = 0; mi < 4; ++mi) {
        float po[4][4];
#pragma unroll
        for (int r = 0; r < 4; ++r)
#pragma unroll
            for (int o = 0; o < 4; ++o) po[r][o] = 0.0f;

#pragma unroll
        for (int ni = 0; ni < 4; ++ni) {
            int h = wn * 64 + ni * 16 + l15;
            f32x4 w4 = ((const f32x4*)W2s)[h];
#pragma unroll
            for (int r = 0; r < 4; ++r) {
                float g = gelu_exact(acc[mi][ni][r] + b1v[ni]);
#pragma unroll
                for (int o = 0; o < 4; ++o) po[r][o] = fmaf(g, w4[o], po[r][o]);
            }
        }
        // reduce over the 16 h-lanes (same token rows)
#pragma unroll
        for (int off = 1; off < 16; off <<= 1) {
#pragma unroll
            for (int r = 0; r < 4; ++r)
#pragma unroll
                for (int o = 0; o < 4; ++o)
                    po[r][o] += __shfl_xor(po[r][o], off, 64);
        }
        // lane (l15) picks its (r,o) pair; static-indexed select
        float v = po[0][0];
#pragma unroll
        for (int rr = 0; rr < 4; ++rr)
#pragma unroll
            for (int oo = 0; oo < 4; ++oo)
                if (l15 == rr * 4 + oo) v = po[rr][oo];
        red[wn][wm * 64 + mi * 16 + l4 * 4 + (l15 >> 2)][l15 & 3] = v;
    }
    __syncthreads();

    if (tid < BM) {
        int b = b0 + tid;
        float o0 = red[0][tid][0] + red[1][tid][0] + b2[p * 4 + 0];
        float o1 = red[0][tid][1] + red[1][tid][1] + b2[p * 4 + 1];
        float o2 = red[0][tid][2] + red[1][tid][2] + b2[p * 4 + 2];
        float o3 = red[0][tid][3] + red[1][tid][3] + b2[p * 4 + 3];
        *reinterpret_cast<float4*>(out_ops + ((size_t)p * B + b) * MAXO) =
            make_float4(o0, o1, o2, o3);

        if (pids[b] == p) {
            float a0 = rintf(o0), a1 = rintf(o1), a2 = rintf(o2), a3 = rintf(o3);
            float r0 = 0.0f, r1 = 0.0f, r2 = 0.0f;
            switch (p) {
                case 0: r0 = a0 + a1; break;
                case 1: r0 = a0 - a1; break;
                case 2: r0 = a0 * a1; break;
                case 3: {
                    float bs = (a1 == 0.0f) ? 1.0f : a1;
                    float m = fmodf(a0, bs);
                    if (m != 0.0f && ((m < 0.0f) != (bs < 0.0f))) m += bs;
                    r0 = m;
                } break;
                case 4: {
                    float bs = (a1 == 0.0f) ? 1.0f : a1;
                    r0 = floorf(a0 / bs);
                } break;
                case 5: { float t = a0 * 60.0f + a1 + a2 * 60.0f + a3; time_decomp(t, r0, r1, r2); } break;
                case 6: { float t = a0 * 60.0f + a1 - (a2 * 60.0f + a3); time_decomp(t, r0, r1, r2); } break;
                case 7: { float t = fabsf(a0 * 60.0f + a1 - (a2 * 60.0f + a3)); time_decomp(t, r0, r1, r2); } break;
                case 8: r0 = (a0 > a1) ? 1.0f : 0.0f; break;
                case 9: r0 = (a0 == a1) ? 1.0f : 0.0f; break;
            }
            size_t ob = (size_t)b * 3;
            out_results[ob + 0] = r0;
            out_results[ob + 1] = r1;
            out_results[ob + 2] = r2;
        }
    }
}

__global__ __launch_bounds__(256) void router_kernel(
    const float* __restrict__ hidden, const float* __restrict__ Wr,
    const float* __restrict__ br, const int* __restrict__ pids,
    float* __restrict__ out_router, float* __restrict__ out_pids, int B)
{
    __shared__ float Wrs[D_ * 12];
    const int tid = threadIdx.x;
    for (int i = tid; i < D_ * P_; i += 256) {
        int k = i / P_;
        int q = i - k * P_;
        Wrs[k * 12 + q] = Wr[i];
    }
    __syncthreads();

    const int lane = tid & 63;
    const int wv   = tid >> 6;
    const int b    = blockIdx.x * 4 + wv;
    const float* hrow = hidden + (size_t)b * D_;

    float acc[P_];
#pragma unroll
    for (int q = 0; q < P_; ++q) acc[q] = 0.0f;

#pragma unroll
    for (int j = 0; j < 8; ++j) {
        int k = j * 64 + lane;
        float hv = hrow[k];
        float wv12[12];
        *reinterpret_cast<float4*>(&wv12[0]) = *reinterpret_cast<const float4*>(&Wrs[k * 12 + 0]);
        *reinterpret_cast<float4*>(&wv12[4]) = *reinterpret_cast<const float4*>(&Wrs[k * 12 + 4]);
        *reinterpret_cast<float2*>(&wv12[8]) = *reinterpret_cast<const float2*>(&Wrs[k * 12 + 8]);
#pragma unroll
        for (int q = 0; q < P_; ++q) acc[q] = fmaf(hv, wv12[q], acc[q]);
    }

#pragma unroll
    for (int off = 1; off < 64; off <<= 1) {
#pragma unroll
        for (int q = 0; q < P_; ++q)
            acc[q] += __shfl_xor(acc[q], off, 64);
    }

    if (lane == 0) {
        float* o = out_router + (size_t)b * P_;
#pragma unroll
        for (int q = 0; q < P_; ++q) o[q] = acc[q] + br[q];
        out_pids[b] = (float)pids[b];
    }
}

extern "C" void kernel_launch(void* const* d_in, const int* in_sizes, int n_in,
                              void* d_out, int out_size, void* d_ws, size_t ws_size,
                              hipStream_t stream) {
    const float* hidden = (const float*)d_in[0];
    const int*   pids   = (const int*)  d_in[1];
    const float* Wr     = (const float*)d_in[2];
    const float* br     = (const float*)d_in[3];
    const float* W1     = (const float*)d_in[4];
    const float* b1     = (const float*)d_in[5];
    const float* W2     = (const float*)d_in[6];
    const float* b2     = (const float*)d_in[7];

    const int B = in_sizes[1];

    float* out         = (float*)d_out;
    float* out_results = out;                                        // [B,3]
    float* out_router  = out + (size_t)B * 3;                        // [B,10]
    float* out_ops     = out + (size_t)B * 13;                       // [P,B,4]
    float* out_pids    = out + (size_t)B * 13 + (size_t)P_ * B * MAXO; // [B]

    f16* W1Thi = (f16*)d_ws;                                         // [P][H][D]
    f16* W1Tlo = W1Thi + (size_t)P_ * H_ * D_;

    cvt_w1_kernel<<<(P_ * D_ * H_) / 256, 256, 0, stream>>>(W1, W1Thi, W1Tlo);

    extractor_kernel<<<(B / BM) * P_, 256, 0, stream>>>(
        hidden, pids, W1Thi, W1Tlo, b1, W2, b2, out_results, out_ops, B);

    router_kernel<<<B / 4, 256, 0, stream>>>(hidden, Wr, br, pids,
                                             out_router, out_pids, B);
}